// Round 8
// baseline (154.963 us; speedup 1.0000x reference)
//
#include <hip/hip_runtime.h>
#include <hip/hip_bf16.h>
#include <string.h>

// Problem constants (fixed by setup_inputs: B=16, T=16, W=256)
#define WDIM 256
#define FRAME (WDIM * WDIM)        // 65536 elems per frame
#define NFRAMES 256                // B*T
#define NTOT ((long long)NFRAMES * FRAME)  // 16777216
#define NBLK 2048                  // 8 sub-blocks per frame
#define SUBV4 2048                 // float4 per sub-block (32 KiB)

// Workspace use is gated on ws_size at launch time (round-7 lesson: the
// 32 MiB stash variant may have written past the real workspace).
//   Stash layout (needs >= 32 MiB + 64 KB):
//     [0, 32 MiB)       uint2 tb[4194304] -- bf16 copy of target (K1-written)
//     [32 MiB, +32 KB)  float4 blk[2048]
//     [.., +16 KB)      double bsum[2048]
//   Fallback layout (round-6 verified, 48 KB):
//     [0, 32 KB)        float4 blk[2048]
//     [32 KB, 48 KB)    double bsum[2048]
// Every used byte is written before it is read each call -> no memset.
#define TB_BYTES (32ull * 1024ull * 1024ull)

__device__ inline unsigned int pack_bf16x2(float a, float b) {
    __hip_bfloat162 h = __float22bfloat162_rn(make_float2(a, b));
    unsigned int u; memcpy(&u, &h, 4); return u;
}

// K1: per-(frame,sub) stats (+ optional bf16 target stash). Each block reads
// 32 KiB of target into registers (8 loads up front), computes block max AND
// tie stats (cnt, sum-row, sum-col) vs its OWN block max from the register
// copy. If do_stash, also writes the chunk to workspace as bf16 (write path
// has headroom; halves K2's read-path bytes for target). Stats valid for the
// frame iff bmax == frame max -- combined exactly in K2.
__global__ __launch_bounds__(256)
void floss_stats(const float* __restrict__ target, float4* __restrict__ blk,
                 uint2* __restrict__ tb, int do_stash) {
    const int bid = blockIdx.x;
    const int fid = bid >> 3, sub = bid & 7;
    const int tid = threadIdx.x;
    const int lane = tid & 63, wave = tid >> 6;

    const float4* __restrict__ t4 =
        (const float4*)(target + (size_t)fid * FRAME) + sub * SUBV4;

    // elem f = sub*8192 + k*1024 + tid*4 + j  ->  row = sub*32 + k*4 + (tid>>6),
    // col = (tid&63)*4 + j
    float4 tv[8];
    #pragma unroll
    for (int k = 0; k < 8; ++k) tv[k] = t4[k * 256 + tid];

    float lmax = -1.0f;
    #pragma unroll
    for (int k = 0; k < 8; ++k)
        lmax = fmaxf(lmax, fmaxf(fmaxf(tv[k].x, tv[k].y), fmaxf(tv[k].z, tv[k].w)));

    if (do_stash) {   // block-uniform branch; fire-and-forget stores
        uint2* __restrict__ tbb = tb + (size_t)bid * SUBV4;
        #pragma unroll
        for (int k = 0; k < 8; ++k)
            tbb[k * 256 + tid] = make_uint2(pack_bf16x2(tv[k].x, tv[k].y),
                                            pack_bf16x2(tv[k].z, tv[k].w));
    }

    // block max: wave shfl reduce + tiny LDS combine
    float wm = lmax;
    #pragma unroll
    for (int off = 32; off > 0; off >>= 1) wm = fmaxf(wm, __shfl_down(wm, off));
    __shared__ float s_wm[4];
    __shared__ float s_st[4][3];
    if (lane == 0) s_wm[wave] = wm;
    __syncthreads();
    const float bmax = fmaxf(fmaxf(s_wm[0], s_wm[1]), fmaxf(s_wm[2], s_wm[3]));

    // tie stats vs block max, from fp32 registers (exact small-int float sums)
    float cnt = 0.0f, sr = 0.0f, sc = 0.0f;
    const float rowb = (float)(sub * 32 + (tid >> 6));
    const float colb = (float)((tid & 63) * 4);
    #pragma unroll
    for (int k = 0; k < 8; ++k) {
        const float row = rowb + (float)(4 * k);
        const float vv[4] = {tv[k].x, tv[k].y, tv[k].z, tv[k].w};
        #pragma unroll
        for (int j = 0; j < 4; ++j)
            if (vv[j] == bmax) { cnt += 1.0f; sr += row; sc += colb + (float)j; }
    }
    #pragma unroll
    for (int off = 32; off > 0; off >>= 1) {
        cnt += __shfl_down(cnt, off);
        sr  += __shfl_down(sr,  off);
        sc  += __shfl_down(sc,  off);
    }
    if (lane == 0) { s_st[wave][0] = cnt; s_st[wave][1] = sr; s_st[wave][2] = sc; }
    __syncthreads();
    if (tid == 0) {
        float c = 0.0f, r = 0.0f, cc = 0.0f;
        #pragma unroll
        for (int w = 0; w < 4; ++w) { c += s_st[w][0]; r += s_st[w][1]; cc += s_st[w][2]; }
        blk[bid] = make_float4(bmax, c, r, cc);
    }
}

// Shared epilogue for both K2 variants: frame-stats combine + weighted BCE
// over register arrays. Bitwise identical math to rounds 0/2/6.
__device__ inline void bce_body(int bid, int fid, int sub, int tid, int lane,
                                int wave, const float4* __restrict__ blk,
                                const float4 (&pv)[8], const float (&tt)[8][4],
                                double* __restrict__ bsum) {
    float fm = -1.0f;
    float4 st[8];
    #pragma unroll
    for (int i = 0; i < 8; ++i) {
        st[i] = blk[(fid << 3) + i];
        fm = fmaxf(fm, st[i].x);
    }
    float cnt = 0.0f, sr = 0.0f, sc = 0.0f;
    #pragma unroll
    for (int i = 0; i < 8; ++i)
        if (st[i].x == fm) { cnt += st[i].y; sr += st[i].z; sc += st[i].w; }
    const float rc = __builtin_amdgcn_rcpf(cnt);   // cnt: small exact int
    const float x = sr * rc;   // mean row
    const float y = sc * rc;   // mean col

    const float rowb = (float)(sub * 32 + (tid >> 6));
    float dc2[4];
    #pragma unroll
    for (int j = 0; j < 4; ++j) {
        const float d = (float)((tid & 63) * 4 + j) - y;
        dc2[j] = d * d;
    }

    float acc0 = 0.0f, acc1 = 0.0f;
    #pragma unroll
    for (int k = 0; k < 8; ++k) {
        const float dr = rowb + (float)(4 * k) - x;
        const float dr2 = dr * dr;
        const float pp[4] = {pv[k].x, pv[k].y, pv[k].z, pv[k].w};
        #pragma unroll
        for (int j = 0; j < 4; ++j) {
            const float dist = __builtin_amdgcn_sqrtf(dr2 + dc2[j]);
            const float w = 256.0f * __builtin_amdgcn_rcpf(dist + 1.0f);
            const float p = pp[j];
            const float lp  = fmaxf(__logf(p), -100.0f);          // v_log_f32
            const float l1p = fmaxf(__logf(1.0f - p), -100.0f);   // exact 1-p for p>=0.5
            // t*lp + (1-t)*l1p == l1p + t*(lp - l1p)
            if (j & 1) acc1 += w * fmaf(tt[k][j], lp - l1p, l1p);
            else       acc0 += w * fmaf(tt[k][j], lp - l1p, l1p);
        }
    }

    float local = acc0 + acc1;
    #pragma unroll
    for (int off = 32; off > 0; off >>= 1) local += __shfl_down(local, off);
    __shared__ float s_acc[4];
    if (lane == 0) s_acc[wave] = local;
    __syncthreads();
    if (tid == 0)
        bsum[bid] = (double)(s_acc[0] + s_acc[1] + s_acc[2] + s_acc[3]);
}

// K2a (stash path): input fp32 from HBM + target bf16 from workspace stash
// (96 MB through the read path instead of 128).
__global__ __launch_bounds__(256)
void floss_bce_tb(const float* __restrict__ input, const uint2* __restrict__ tb,
                  const float4* __restrict__ blk, double* __restrict__ bsum) {
    const int bid = blockIdx.x;
    const int fid = bid >> 3, sub = bid & 7;
    const int tid = threadIdx.x;
    const int lane = tid & 63, wave = tid >> 6;

    const float4* __restrict__ p4 =
        (const float4*)(input + (size_t)fid * FRAME) + sub * SUBV4;
    const uint2* __restrict__ tbb = tb + (size_t)bid * SUBV4;

    float4 pv[8];
    uint2 tw[8];
    #pragma unroll
    for (int k = 0; k < 8; ++k) pv[k] = p4[k * 256 + tid];
    #pragma unroll
    for (int k = 0; k < 8; ++k) tw[k] = tbb[k * 256 + tid];

    float tt[8][4];
    #pragma unroll
    for (int k = 0; k < 8; ++k) {
        tt[k][0] = __uint_as_float(tw[k].x << 16);
        tt[k][1] = __uint_as_float(tw[k].x & 0xffff0000u);
        tt[k][2] = __uint_as_float(tw[k].y << 16);
        tt[k][3] = __uint_as_float(tw[k].y & 0xffff0000u);
    }
    bce_body(bid, fid, sub, tid, lane, wave, blk, pv, tt, bsum);
}

// K2b (fallback, round-6 verified): input + fp32 target both from global.
__global__ __launch_bounds__(256)
void floss_bce_t(const float* __restrict__ input, const float* __restrict__ target,
                 const float4* __restrict__ blk, double* __restrict__ bsum) {
    const int bid = blockIdx.x;
    const int fid = bid >> 3, sub = bid & 7;
    const int tid = threadIdx.x;
    const int lane = tid & 63, wave = tid >> 6;

    const float4* __restrict__ t4 =
        (const float4*)(target + (size_t)fid * FRAME) + sub * SUBV4;
    const float4* __restrict__ p4 =
        (const float4*)(input + (size_t)fid * FRAME) + sub * SUBV4;

    float4 pv[8], tv[8];
    #pragma unroll
    for (int k = 0; k < 8; ++k) pv[k] = p4[k * 256 + tid];
    #pragma unroll
    for (int k = 0; k < 8; ++k) tv[k] = t4[k * 256 + tid];

    float tt[8][4];
    #pragma unroll
    for (int k = 0; k < 8; ++k) {
        tt[k][0] = tv[k].x; tt[k][1] = tv[k].y;
        tt[k][2] = tv[k].z; tt[k][3] = tv[k].w;
    }
    bce_body(bid, fid, sub, tid, lane, wave, blk, pv, tt, bsum);
}

// K3: reduce 2048 per-block doubles, write final loss. (~4 us; 25x cheaper
// than any single-line device-wide ticket -- see round-5 post-mortem.)
__global__ __launch_bounds__(1024)
void floss_final(const double* __restrict__ bsum, float* __restrict__ out) {
    const int tid = threadIdx.x;
    const int lane = tid & 63, wave = tid >> 6;
    double v = bsum[tid] + bsum[tid + 1024];
    #pragma unroll
    for (int off = 32; off > 0; off >>= 1) v += __shfl_down(v, off);
    __shared__ double sd[16];
    if (lane == 0) sd[wave] = v;
    __syncthreads();
    if (tid == 0) {
        double s = 0.0;
        #pragma unroll
        for (int w = 0; w < 16; ++w) s += sd[w];
        out[0] = (float)(-s / (double)NTOT);
    }
}

extern "C" void kernel_launch(void* const* d_in, const int* in_sizes, int n_in,
                              void* d_out, int out_size, void* d_ws, size_t ws_size,
                              hipStream_t stream) {
    const float* input  = (const float*)d_in[0];  // [B,1,T,W,W] == flat [B,T,W,W]
    const float* target = (const float*)d_in[1];  // [B,T,W,W]
    float* out = (float*)d_out;

    const int use_stash = (ws_size >= TB_BYTES + 64ull * 1024ull) ? 1 : 0;

    if (use_stash) {
        uint2*  tb   = (uint2*)d_ws;                              // 32 MiB
        float4* blk  = (float4*)((char*)d_ws + TB_BYTES);         // 2048 float4
        double* bsum = (double*)((char*)d_ws + TB_BYTES + NBLK * sizeof(float4));
        floss_stats<<<NBLK, 256, 0, stream>>>(target, blk, tb, 1);
        floss_bce_tb<<<NBLK, 256, 0, stream>>>(input, tb, blk, bsum);
        floss_final<<<1, 1024, 0, stream>>>(bsum, out);
    } else {
        float4* blk  = (float4*)d_ws;                             // 2048 float4
        double* bsum = (double*)((char*)d_ws + NBLK * sizeof(float4));
        floss_stats<<<NBLK, 256, 0, stream>>>(target, blk, (uint2*)d_ws /*unused*/, 0);
        floss_bce_t<<<NBLK, 256, 0, stream>>>(input, target, blk, bsum);
        floss_final<<<1, 1024, 0, stream>>>(bsum, out);
    }
}

// Round 9
// 144.858 us; speedup vs baseline: 1.0698x; 1.0698x over previous
//
#include <hip/hip_runtime.h>

// Problem constants (fixed by setup_inputs: B=16, T=16, W=256)
#define WDIM 256
#define FRAME (WDIM * WDIM)        // 65536 elems per frame
#define NFRAMES 256                // B*T
#define NTOT ((long long)NFRAMES * FRAME)  // 16777216
#define NBLK 2048                  // 8 sub-blocks per frame
#define SUBV4 2048                 // float4 per sub-block (32 KiB)

// ws layout: float4 blk[2048] (32 KB) | double bsum[2048] (16 KB). 48 KB total,
// fully overwritten every call (no init kernel / memset needed).
//
// This is the round-2 configuration verbatim -- the best-measured variant of
// this session (146.1 us, absmax 0.0). Rounds 3-8 tested: monolithic block
// (latency-bound), register stash across sync (spills), atomic spin / global
// ticket (XCD line-bounce serializers), cooperative launch (harness-fatal),
// up-front-load restructuring (neutral), bf16 target stash (neutral).
// Conclusion: the two streaming passes run at ~4.6 TB/s read, within ~10% of
// the read-path ceiling; the rest of the bench time is harness-fixed.

// K1: per-(frame,sub) stats. Each block reads 32 KiB of target into registers,
// computes block max AND tie stats (cnt, sum-row, sum-col) vs its OWN block
// max from the register copy. A block's stats are valid for the frame iff its
// bmax equals the frame max -- combined exactly in K2. No rescan, no atomics.
__global__ __launch_bounds__(256)
void floss_stats(const float* __restrict__ target, float4* __restrict__ blk) {
    const int bid = blockIdx.x;
    const int fid = bid >> 3, sub = bid & 7;
    const int tid = threadIdx.x;
    const int lane = tid & 63, wave = tid >> 6;

    const float4* __restrict__ t4 =
        (const float4*)(target + (size_t)fid * FRAME) + sub * SUBV4;

    // elem f = sub*8192 + k*1024 + tid*4 + j  ->  row = sub*32 + k*4 + (tid>>6),
    // col = (tid&63)*4 + j
    float4 tv[8];
    #pragma unroll
    for (int k = 0; k < 8; ++k) tv[k] = t4[k * 256 + tid];

    float lmax = -1.0f;
    #pragma unroll
    for (int k = 0; k < 8; ++k)
        lmax = fmaxf(lmax, fmaxf(fmaxf(tv[k].x, tv[k].y), fmaxf(tv[k].z, tv[k].w)));

    // block max: wave shfl reduce + tiny LDS combine
    float wm = lmax;
    #pragma unroll
    for (int off = 32; off > 0; off >>= 1) wm = fmaxf(wm, __shfl_down(wm, off));
    __shared__ float s_wm[4];
    __shared__ float s_st[4][3];
    if (lane == 0) s_wm[wave] = wm;
    __syncthreads();
    const float bmax = fmaxf(fmaxf(s_wm[0], s_wm[1]), fmaxf(s_wm[2], s_wm[3]));

    // tie stats vs block max, from registers (exact small-int float sums)
    float cnt = 0.0f, sr = 0.0f, sc = 0.0f;
    const float rowb = (float)(sub * 32 + (tid >> 6));
    const float colb = (float)((tid & 63) * 4);
    #pragma unroll
    for (int k = 0; k < 8; ++k) {
        const float row = rowb + (float)(4 * k);
        const float vv[4] = {tv[k].x, tv[k].y, tv[k].z, tv[k].w};
        #pragma unroll
        for (int j = 0; j < 4; ++j)
            if (vv[j] == bmax) { cnt += 1.0f; sr += row; sc += colb + (float)j; }
    }
    #pragma unroll
    for (int off = 32; off > 0; off >>= 1) {
        cnt += __shfl_down(cnt, off);
        sr  += __shfl_down(sr,  off);
        sc  += __shfl_down(sc,  off);
    }
    if (lane == 0) { s_st[wave][0] = cnt; s_st[wave][1] = sr; s_st[wave][2] = sc; }
    __syncthreads();
    if (tid == 0) {
        float c = 0.0f, r = 0.0f, cc = 0.0f;
        #pragma unroll
        for (int w = 0; w < 4; ++w) { c += s_st[w][0]; r += s_st[w][1]; cc += s_st[w][2]; }
        blk[bid] = make_float4(bmax, c, r, cc);
    }
}

// K2: weighted BCE. Combine the frame's 8 stat records (uniform scalar loads),
// then stream t+p once. High occupancy, no big LDS, no cross-phase barriers.
__global__ __launch_bounds__(256)
void floss_bce(const float* __restrict__ input, const float* __restrict__ target,
               const float4* __restrict__ blk, double* __restrict__ bsum) {
    const int bid = blockIdx.x;
    const int fid = bid >> 3, sub = bid & 7;
    const int tid = threadIdx.x;
    const int lane = tid & 63, wave = tid >> 6;

    const float4* __restrict__ t4 =
        (const float4*)(target + (size_t)fid * FRAME) + sub * SUBV4;
    const float4* __restrict__ p4 =
        (const float4*)(input + (size_t)fid * FRAME) + sub * SUBV4;

    // frame stats: max of 8 block maxes; sum stats of blocks matching it.
    // Exact float compares + exact small-int sums.
    float fm = -1.0f;
    float4 st[8];
    #pragma unroll
    for (int i = 0; i < 8; ++i) {
        st[i] = blk[(fid << 3) + i];            // uniform address -> s_load
        fm = fmaxf(fm, st[i].x);
    }
    float cnt = 0.0f, sr = 0.0f, sc = 0.0f;
    #pragma unroll
    for (int i = 0; i < 8; ++i)
        if (st[i].x == fm) { cnt += st[i].y; sr += st[i].z; sc += st[i].w; }
    const float rc = __builtin_amdgcn_rcpf(cnt);   // cnt: small exact int
    const float x = sr * rc;   // mean row
    const float y = sc * rc;   // mean col

    const float rowb = (float)(sub * 32 + (tid >> 6));
    float dc2[4];
    #pragma unroll
    for (int j = 0; j < 4; ++j) {
        const float d = (float)((tid & 63) * 4 + j) - y;
        dc2[j] = d * d;
    }

    float acc0 = 0.0f, acc1 = 0.0f;
    #pragma unroll
    for (int k = 0; k < 8; ++k) {
        const float4 tv = t4[k * 256 + tid];
        const float4 pv = p4[k * 256 + tid];
        const float dr = rowb + (float)(4 * k) - x;
        const float dr2 = dr * dr;
        const float tt[4] = {tv.x, tv.y, tv.z, tv.w};
        const float pp[4] = {pv.x, pv.y, pv.z, pv.w};
        #pragma unroll
        for (int j = 0; j < 4; ++j) {
            const float dist = __builtin_amdgcn_sqrtf(dr2 + dc2[j]);
            const float w = 256.0f * __builtin_amdgcn_rcpf(dist + 1.0f);
            const float p = pp[j];
            const float lp  = fmaxf(__logf(p), -100.0f);          // v_log_f32
            const float l1p = fmaxf(__logf(1.0f - p), -100.0f);   // exact 1-p for p>=0.5
            // t*lp + (1-t)*l1p == l1p + t*(lp - l1p)
            if (j & 1) acc1 += w * fmaf(tt[j], lp - l1p, l1p);
            else       acc0 += w * fmaf(tt[j], lp - l1p, l1p);
        }
    }

    float local = acc0 + acc1;
    #pragma unroll
    for (int off = 32; off > 0; off >>= 1) local += __shfl_down(local, off);
    __shared__ float s_acc[4];
    if (lane == 0) s_acc[wave] = local;
    __syncthreads();
    if (tid == 0)
        bsum[bid] = (double)(s_acc[0] + s_acc[1] + s_acc[2] + s_acc[3]);
}

// K3: reduce 2048 per-block doubles, write final loss.
__global__ __launch_bounds__(1024)
void floss_final(const double* __restrict__ bsum, float* __restrict__ out) {
    const int tid = threadIdx.x;
    const int lane = tid & 63, wave = tid >> 6;
    double v = bsum[tid] + bsum[tid + 1024];
    #pragma unroll
    for (int off = 32; off > 0; off >>= 1) v += __shfl_down(v, off);
    __shared__ double sd[16];
    if (lane == 0) sd[wave] = v;
    __syncthreads();
    if (tid == 0) {
        double s = 0.0;
        #pragma unroll
        for (int w = 0; w < 16; ++w) s += sd[w];
        out[0] = (float)(-s / (double)NTOT);
    }
}

extern "C" void kernel_launch(void* const* d_in, const int* in_sizes, int n_in,
                              void* d_out, int out_size, void* d_ws, size_t ws_size,
                              hipStream_t stream) {
    const float* input  = (const float*)d_in[0];  // [B,1,T,W,W] == flat [B,T,W,W]
    const float* target = (const float*)d_in[1];  // [B,T,W,W]
    float* out = (float*)d_out;
    float4* blk  = (float4*)d_ws;                          // 2048 float4 (32 KB)
    double* bsum = (double*)((char*)d_ws + NBLK * sizeof(float4)); // 2048 doubles

    floss_stats<<<NBLK, 256, 0, stream>>>(target, blk);
    floss_bce<<<NBLK, 256, 0, stream>>>(input, target, blk, bsum);
    floss_final<<<1, 1024, 0, stream>>>(bsum, out);
}